// Round 1
// baseline (518.958 us; speedup 1.0000x reference)
//
#include <hip/hip_runtime.h>

// ---------------- problem constants ----------------
#define N_NODES   20000
#define N_EDGES   640000
#define CF        313      // FEAT + NUM_SEM
#define HID       128
#define KC        320      // child K padded to mult of 32 (313 -> 320), 10 ksteps
#define KE        288      // edge K padded (268 -> 288), 9 ksteps
#define ROWB      640      // LDS A-tile row stride in bytes (both kernels)

typedef __attribute__((ext_vector_type(8))) short short8;
typedef __attribute__((ext_vector_type(4))) float f32x4;

static __device__ __forceinline__ unsigned short f2bf(float f) {
    unsigned u = __float_as_uint(f);
    u = u + 0x7FFFu + ((u >> 16) & 1u);   // RNE
    return (unsigned short)(u >> 16);
}

// ---------------- weight pre-convert: W (KxN f32) -> W^T (N x Kpad bf16) ----
__global__ void prep_weights(const float* __restrict__ Wc,
                             const float* __restrict__ We0,
                             const float* __restrict__ We1,
                             unsigned short* __restrict__ WcT,
                             unsigned short* __restrict__ We0T,
                             unsigned short* __restrict__ We1T) {
    int g = blockIdx.x * 256 + threadIdx.x;           // 448*256 = 114688 exactly
    if (g < 128 * KC) {
        int n = g / KC, k = g % KC;
        WcT[g] = f2bf(k < CF ? Wc[k * 128 + n] : 0.f);
    } else if (g < 128 * KC + 128 * KE) {
        int h = g - 128 * KC;
        int n = h / KE, k = h % KE;
        We0T[h] = f2bf(k < 268 ? We0[k * 128 + n] : 0.f);
    } else {
        int h = g - 128 * KC - 128 * KE;
        int n = h / KE, k = h % KE;
        We1T[h] = f2bf(k < 268 ? We1[k * 128 + n] : 0.f);
    }
}

// ---------------- child encoder: h = relu(cf @ Wc + bc) * exists ------------
// 313 blocks x 256 thr, one 64-row tile each. Writes h (bf16) + colmax slice 0.
__global__ __launch_bounds__(256, 2)
void child_gemm(const float* __restrict__ cf,          // [20000][313]
                const float* __restrict__ exists,      // [20000]
                const unsigned short* __restrict__ WT, // [128][320] bf16
                const float* __restrict__ bias,        // [128]
                unsigned short* __restrict__ hbf,      // [20000][128] bf16 out
                unsigned int* __restrict__ pmax)       // [128] f32-bits, zeroed
{
    __shared__ __align__(16) unsigned char Alds[64 * ROWB];

    const int tid  = threadIdx.x;
    const int lane = tid & 63;
    const int wave = tid >> 6;
    const int n0   = wave * 32;
    const int tile = blockIdx.x;
    const int row0 = tile * 64;

    // B fragments: 10 ksteps x 2 ntiles, register-resident
    short8 bfrag[10][2];
    {
        int col  = n0 + (lane & 15);
        int krow = (lane >> 4) * 8;
        #pragma unroll
        for (int ks = 0; ks < 10; ++ks)
            #pragma unroll
            for (int nt = 0; nt < 2; ++nt)
                bfrag[ks][nt] = *(const short8*)(WT + (col + nt * 16) * KC + ks * 32 + krow);
    }
    float bv[2];
    bv[0] = bias[n0 + (lane & 15)];
    bv[1] = bias[n0 + 16 + (lane & 15)];

    // ---- gather 64 rows of child_feats -> bf16, padded to 320, swizzled ----
    {
        int r = tid >> 2, p = tid & 3;
        int node = row0 + r;
        bool valid = node < N_NODES;
        const float* g = cf + (size_t)node * CF;
        unsigned rbase = r * ROWB;
        unsigned sw = (r & 7) << 4;
        #pragma unroll
        for (int i = 0; i < 10; ++i) {
            int c = p + i * 4;                 // chunk 0..39, 8 bf16 each
            short8 v = {};
            if (valid) {
                #pragma unroll
                for (int kk = 0; kk < 8; ++kk) {
                    int k = c * 8 + kk;
                    if (k < CF) v[kk] = (short)f2bf(g[k]);
                }
            }
            *(short8*)(Alds + ((rbase + c * 16) ^ sw)) = v;
        }
    }
    __syncthreads();

    f32x4 acc[4][2] = {};
    {
        int arow = lane & 15;
        unsigned kb = (lane >> 4) * 16;
        #pragma unroll
        for (int ks = 0; ks < 10; ++ks)
            #pragma unroll
            for (int mt = 0; mt < 4; ++mt) {
                int row = mt * 16 + arow;
                short8 a = *(const short8*)(Alds + (((unsigned)row * ROWB + ks * 64 + kb) ^ ((row & 7) << 4)));
                acc[mt][0] = __builtin_amdgcn_mfma_f32_16x16x32_bf16(a, bfrag[ks][0], acc[mt][0], 0, 0, 0);
                acc[mt][1] = __builtin_amdgcn_mfma_f32_16x16x32_bf16(a, bfrag[ks][1], acc[mt][1], 0, 0, 0);
            }
    }

    // ---- epilogue: bias, relu, *exists, store bf16, column-max ----
    {
        int rb = (lane >> 4) * 4;
        #pragma unroll
        for (int nt = 0; nt < 2; ++nt) {
            int col = n0 + nt * 16 + (lane & 15);
            float m = 0.f;
            #pragma unroll
            for (int mt = 0; mt < 4; ++mt)
                #pragma unroll
                for (int j = 0; j < 4; ++j) {
                    int node = row0 + mt * 16 + rb + j;
                    float v = 0.f;
                    if (node < N_NODES) {
                        v = fmaxf(acc[mt][nt][j] + bv[nt], 0.f) * exists[node];
                        hbf[node * 128 + col] = f2bf(v);
                    }
                    m = fmaxf(m, v);
                }
            m = fmaxf(m, __shfl_xor(m, 16));
            m = fmaxf(m, __shfl_xor(m, 32));
            if ((lane >> 4) == 0)
                atomicMax(pmax + col, __float_as_uint(m));
        }
    }
}

// ---------------- edge layer: msg = relu([h[s]|h[d]|ef] @ W + b); ----------
// h_next[s] = max over edges (atomicMax on f32 bits, buffer pre-zeroed)
__global__ __launch_bounds__(256, 2)
void edge_layer(const unsigned short* __restrict__ hbf,   // [20000][128] bf16
                const int* __restrict__ eidx,             // [640000][2]
                const float* __restrict__ onehot,         // [640000][4]
                const float* __restrict__ efeat,          // [640000][8]
                const unsigned short* __restrict__ WT,    // [128][288] bf16
                const float* __restrict__ bias,           // [128]
                unsigned int* __restrict__ hnext)         // [20000][128] zeroed
{
    __shared__ __align__(16) unsigned char Alds[64 * ROWB];
    __shared__ int srcids[64];

    const int tid  = threadIdx.x;
    const int lane = tid & 63;
    const int wave = tid >> 6;
    const int n0   = wave * 32;

    short8 bfrag[9][2];
    {
        int col  = n0 + (lane & 15);
        int krow = (lane >> 4) * 8;
        #pragma unroll
        for (int ks = 0; ks < 9; ++ks)
            #pragma unroll
            for (int nt = 0; nt < 2; ++nt)
                bfrag[ks][nt] = *(const short8*)(WT + (col + nt * 16) * KE + ks * 32 + krow);
    }
    float bv[2];
    bv[0] = bias[n0 + (lane & 15)];
    bv[1] = bias[n0 + 16 + (lane & 15)];

    const int ntiles = N_EDGES / 64;   // 10000 exactly
    for (int tile = blockIdx.x; tile < ntiles; tile += gridDim.x) {
        __syncthreads();               // protect LDS vs previous iteration
        // ---- gather A rows: [h[src](128) | h[dst](128) | oh(4)+ef(8) | pad] ----
        {
            int r = tid >> 2, p = tid & 3;
            int e = tile * 64 + r;
            int s = eidx[2 * e], d = eidx[2 * e + 1];
            if (p == 0) srcids[r] = s;
            const short8* hs = (const short8*)(hbf + s * 128);
            const short8* hd = (const short8*)(hbf + d * 128);
            unsigned rbase = r * ROWB;
            unsigned sw = (r & 7) << 4;
            #pragma unroll
            for (int i = 0; i < 8; ++i) {
                int c = p + i * 4;                   // chunks 0..31
                short8 v = (c < 16) ? hs[c] : hd[c - 16];
                *(short8*)(Alds + ((rbase + c * 16) ^ sw)) = v;
            }
            // tail chunk 32+p: ef then zero pad
            short8 v = {};
            if (p == 0) {
                const float* oh = onehot + 4 * e;
                const float* ef = efeat + 8 * e;
                v[0] = (short)f2bf(oh[0]); v[1] = (short)f2bf(oh[1]);
                v[2] = (short)f2bf(oh[2]); v[3] = (short)f2bf(oh[3]);
                v[4] = (short)f2bf(ef[0]); v[5] = (short)f2bf(ef[1]);
                v[6] = (short)f2bf(ef[2]); v[7] = (short)f2bf(ef[3]);
            } else if (p == 1) {
                const float* ef = efeat + 8 * e;
                v[0] = (short)f2bf(ef[4]); v[1] = (short)f2bf(ef[5]);
                v[2] = (short)f2bf(ef[6]); v[3] = (short)f2bf(ef[7]);
            }
            *(short8*)(Alds + ((rbase + (32 + p) * 16) ^ sw)) = v;
        }
        __syncthreads();

        f32x4 acc[4][2] = {};
        {
            int arow = lane & 15;
            unsigned kb = (lane >> 4) * 16;
            #pragma unroll
            for (int ks = 0; ks < 9; ++ks)
                #pragma unroll
                for (int mt = 0; mt < 4; ++mt) {
                    int row = mt * 16 + arow;
                    short8 a = *(const short8*)(Alds + (((unsigned)row * ROWB + ks * 64 + kb) ^ ((row & 7) << 4)));
                    acc[mt][0] = __builtin_amdgcn_mfma_f32_16x16x32_bf16(a, bfrag[ks][0], acc[mt][0], 0, 0, 0);
                    acc[mt][1] = __builtin_amdgcn_mfma_f32_16x16x32_bf16(a, bfrag[ks][1], acc[mt][1], 0, 0, 0);
                }
        }

        // ---- epilogue: bias+relu, atomicMax into h_next[src] ----
        {
            int rb = (lane >> 4) * 4;
            int colbase = n0 + (lane & 15);
            #pragma unroll
            for (int mt = 0; mt < 4; ++mt)
                #pragma unroll
                for (int j = 0; j < 4; ++j) {
                    int s = srcids[mt * 16 + rb + j];
                    #pragma unroll
                    for (int nt = 0; nt < 2; ++nt) {
                        float v = fmaxf(acc[mt][nt][j] + bv[nt], 0.f);
                        atomicMax(hnext + s * 128 + colbase + nt * 16, __float_as_uint(v));
                    }
                }
        }
    }
}

// ---------------- h_next (f32) -> h (bf16) + column max into parent slice ---
__global__ void convert_colmax(const unsigned int* __restrict__ hnext,
                               unsigned short* __restrict__ hbf,
                               unsigned int* __restrict__ pslice) {
    int g = blockIdx.x * 256 + threadIdx.x;   // 512*256 = 131072
    int c = g & 127;
    unsigned m = 0;
    for (int r = g >> 7; r < N_NODES; r += 1024) {
        unsigned u = hnext[r * 128 + c];
        hbf[r * 128 + c] = f2bf(__uint_as_float(u));
        m = max(m, u);                        // valid: non-negative floats
    }
    atomicMax(pslice + c, m);
}

// ---------------- final: out = relu(parent @ Wp + bp) ----------------------
__global__ void final_gemm(const float* __restrict__ parent,  // [384]
                           const float* __restrict__ Wp,      // [384][256]
                           const float* __restrict__ bp,      // [256]
                           float* __restrict__ out) {          // [256]
    __shared__ float p[384];
    int t = threadIdx.x;
    for (int i = t; i < 384; i += 256) p[i] = parent[i];
    __syncthreads();
    float s = bp[t];
    for (int k = 0; k < 384; ++k) s += p[k] * Wp[k * 256 + t];
    out[t] = fmaxf(s, 0.f);
}

// ---------------- launch ----------------------------------------------------
extern "C" void kernel_launch(void* const* d_in, const int* in_sizes, int n_in,
                              void* d_out, int out_size, void* d_ws, size_t ws_size,
                              hipStream_t stream) {
    const float* child_feats  = (const float*)d_in[0];
    const float* child_exists = (const float*)d_in[1];
    const float* onehot       = (const float*)d_in[2];
    const float* efeat        = (const float*)d_in[3];
    const int*   eidx         = (const int*)d_in[4];
    const float* Wc  = (const float*)d_in[5];
    const float* bc  = (const float*)d_in[6];
    const float* We0 = (const float*)d_in[7];
    const float* be0 = (const float*)d_in[8];
    const float* We1 = (const float*)d_in[9];
    const float* be1 = (const float*)d_in[10];
    const float* Wp  = (const float*)d_in[11];
    const float* bp  = (const float*)d_in[12];

    char* ws = (char*)d_ws;
    unsigned short* hbf   = (unsigned short*)(ws);                 // 5,120,000 B
    unsigned int*   hnext = (unsigned int*)(ws + 5120000);         // 10,240,000 B
    unsigned short* WcT   = (unsigned short*)(ws + 15360000);      // 81,920 B
    unsigned short* We0T  = (unsigned short*)(ws + 15441920);      // 73,728 B
    unsigned short* We1T  = (unsigned short*)(ws + 15515648);      // 73,728 B
    unsigned int*   parent= (unsigned int*)(ws + 15589376);        // 1,536 B

    hipMemsetAsync(parent, 0, 384 * 4, stream);
    prep_weights<<<448, 256, 0, stream>>>(Wc, We0, We1, WcT, We0T, We1T);
    child_gemm<<<313, 256, 0, stream>>>(child_feats, child_exists, WcT, bc, hbf, parent);

    hipMemsetAsync(hnext, 0, N_NODES * 128 * 4, stream);
    edge_layer<<<2048, 256, 0, stream>>>(hbf, eidx, onehot, efeat, We0T, be0, hnext);
    convert_colmax<<<512, 256, 0, stream>>>(hnext, hbf, parent + 128);

    hipMemsetAsync(hnext, 0, N_NODES * 128 * 4, stream);
    edge_layer<<<2048, 256, 0, stream>>>(hbf, eidx, onehot, efeat, We1T, be1, hnext);
    convert_colmax<<<512, 256, 0, stream>>>(hnext, hbf, parent + 256);

    final_gemm<<<1, 256, 0, stream>>>((const float*)parent, Wp, bp, (float*)d_out);
}